// Round 1
// baseline (6359.708 us; speedup 1.0000x reference)
//
#include <hip/hip_runtime.h>
#include <cmath>

namespace {

constexpr int HEADS = 8;
constexpr int Bn = 4;
constexpr int Tn = 2048;
constexpr int Dn = 128;
constexpr float QK_SCALE = 0.2973017787506803f;  // 128^(-1/4)

// LDS tiles are stored row-major with float4-group XOR swizzle:
// physical group = g ^ ((row>>2)&7). Makes every read pattern below <=2-way
// bank aliasing (free), padding can't do that for the tx-indexed operand.
__device__ __forceinline__ float4 lds_ld4(const float* buf, int r, int g, int ldw) {
  int gs = g ^ ((r >> 2) & 7);
  return *reinterpret_cast<const float4*>(buf + r * ldw + gs * 4);
}
__device__ __forceinline__ void lds_st4(float* buf, int r, int g, int ldw, float4 v) {
  int gs = g ^ ((r >> 2) & 7);
  *reinterpret_cast<float4*>(buf + r * ldw + gs * 4) = v;
}

// Stage NROWS x NCOLS floats from global (leading dim ld) into swizzled LDS.
template <int NROWS, int NCOLS>
__device__ __forceinline__ void stage_tile(float* dst, const float* src, int ld, int tid) {
  constexpr int NG = NCOLS / 4;
  constexpr int TOT = NROWS * NG;
#pragma unroll
  for (int fid = tid; fid < TOT; fid += 256) {
    int r = fid / NG;
    int g = fid % NG;
    float4 v = *reinterpret_cast<const float4*>(src + r * ld + g * 4);
    lds_st4(dst, r, g, NCOLS, v);
  }
}

// One 64-wide k-chunk of a 64x64 output tile: acc[4][4] += X(64xk) * W(64xk)^T
__device__ __forceinline__ void gemm64_step(const float* sX, const float* sW, int ty, int tx,
                                            float acc[4][4]) {
#pragma unroll
  for (int g = 0; g < 16; ++g) {
    float4 a4[4], b4[4];
#pragma unroll
    for (int i = 0; i < 4; ++i) a4[i] = lds_ld4(sX, ty * 4 + i, g, 64);
#pragma unroll
    for (int j = 0; j < 4; ++j) b4[j] = lds_ld4(sW, tx * 4 + j, g, 64);
#pragma unroll
    for (int i = 0; i < 4; ++i)
#pragma unroll
      for (int j = 0; j < 4; ++j)
        acc[i][j] += a4[i].x * b4[j].x + a4[i].y * b4[j].y + a4[i].z * b4[j].z +
                     a4[i].w * b4[j].w;
  }
}

// ---------------- QKV projection ----------------
// out[n = h*128+d] = sum_k x[bt,k] * W[n,k]   (scaled for Q,K)
// written as dst[((b*H+h)*T + t)*128 + d]
__global__ __launch_bounds__(256) void proj_kernel(
    const float* __restrict__ x, const float* __restrict__ Wq, const float* __restrict__ Wk,
    const float* __restrict__ Wv, float* __restrict__ Q, float* __restrict__ Kb,
    float* __restrict__ Vb) {
  __shared__ float sX[64 * 64];
  __shared__ float sW[64 * 64];
  const int tid = threadIdx.x;
  const int ty = tid >> 4, tx = tid & 15;
  const int rt = blockIdx.x;  // 0..127  (row tile over b*T)
  const int ct = blockIdx.y;  // 0..47   (col tile over 3*1024)
  const int sel = ct >> 4;
  const float* W = (sel == 0) ? Wq : (sel == 1) ? Wk : Wv;
  float* dst = (sel == 0) ? Q : (sel == 1) ? Kb : Vb;
  const float scale = (sel == 2) ? 1.0f : QK_SCALE;
  const int n0 = (ct & 15) * 64;
  const int r0 = rt * 64;

  float acc[4][4] = {};
#pragma unroll
  for (int kc = 0; kc < 2; ++kc) {
    __syncthreads();
    stage_tile<64, 64>(sX, x + (size_t)r0 * 128 + kc * 64, 128, tid);
    stage_tile<64, 64>(sW, W + (size_t)n0 * 128 + kc * 64, 128, tid);
    __syncthreads();
    gemm64_step(sX, sW, ty, tx, acc);
  }

  const int b = r0 >> 11;      // r0 / 2048 (tiles never straddle b)
  const int t0 = r0 & 2047;
  const int h = n0 >> 7;
  const int d0 = n0 & 127;
#pragma unroll
  for (int i = 0; i < 4; ++i) {
    const int t = t0 + ty * 4 + i;
    float4 v = make_float4(acc[i][0] * scale, acc[i][1] * scale, acc[i][2] * scale,
                           acc[i][3] * scale);
    *reinterpret_cast<float4*>(dst + (((size_t)(b * HEADS + h) * Tn + t) * Dn) + d0 + tx * 4) = v;
  }
}

// ---------------- flash attention ----------------
// per block: one (b,h), 64 q rows. Streams K/V in 64-row s-tiles.
__global__ __launch_bounds__(256) void flash_kernel(const float* __restrict__ Q,
                                                    const float* __restrict__ Kb,
                                                    const float* __restrict__ Vb,
                                                    float* __restrict__ Ob) {
  __shared__ float sQ[64 * 128];  // 32 KB
  __shared__ float sA[64 * 64];   // 16 KB (K chunk, then V chunk)
  __shared__ float sP[64 * 64];   // 16 KB
  const int tid = threadIdx.x;
  const int ty = tid >> 4, tx = tid & 15;
  const int qt = blockIdx.x;  // 0..31
  const int bh = blockIdx.y;  // 0..31
  const float* Qp = Q + (size_t)bh * Tn * Dn + (size_t)qt * 64 * Dn;
  const float* Kp = Kb + (size_t)bh * Tn * Dn;
  const float* Vp = Vb + (size_t)bh * Tn * Dn;

  stage_tile<64, 128>(sQ, Qp, 128, tid);

  float acc[2][4][4] = {};
  float m[4], l[4];
#pragma unroll
  for (int i = 0; i < 4; ++i) { m[i] = -INFINITY; l[i] = 0.0f; }

  for (int st = 0; st < Tn / 64; ++st) {
    const float* Kt = Kp + (size_t)st * 64 * Dn;
    const float* Vt = Vp + (size_t)st * 64 * Dn;

    // S = Qtile @ Ktile^T, k chunked by 64
    float s[4][4] = {};
#pragma unroll
    for (int kc = 0; kc < 2; ++kc) {
      __syncthreads();
      stage_tile<64, 64>(sA, Kt + kc * 64, 128, tid);
      __syncthreads();
#pragma unroll
      for (int g = 0; g < 16; ++g) {
        float4 q4[4], k4[4];
#pragma unroll
        for (int i = 0; i < 4; ++i) q4[i] = lds_ld4(sQ, ty * 4 + i, kc * 16 + g, 128);
#pragma unroll
        for (int j = 0; j < 4; ++j) k4[j] = lds_ld4(sA, tx * 4 + j, g, 64);
#pragma unroll
        for (int i = 0; i < 4; ++i)
#pragma unroll
          for (int j = 0; j < 4; ++j)
            s[i][j] += q4[i].x * k4[j].x + q4[i].y * k4[j].y + q4[i].z * k4[j].z +
                       q4[i].w * k4[j].w;
      }
    }

    // online softmax over the 64 cols (spread across 16 tx lanes)
#pragma unroll
    for (int i = 0; i < 4; ++i) {
      float mt = fmaxf(fmaxf(s[i][0], s[i][1]), fmaxf(s[i][2], s[i][3]));
      for (int off = 8; off; off >>= 1) mt = fmaxf(mt, __shfl_xor(mt, off, 16));
      const float mn = fmaxf(m[i], mt);
      const float al = expf(m[i] - mn);  // 0 when m was -inf
      float rs = 0.0f;
#pragma unroll
      for (int j = 0; j < 4; ++j) {
        s[i][j] = expf(s[i][j] - mn);
        rs += s[i][j];
      }
      for (int off = 8; off; off >>= 1) rs += __shfl_xor(rs, off, 16);
      l[i] = l[i] * al + rs;
      m[i] = mn;
#pragma unroll
      for (int cc = 0; cc < 2; ++cc)
#pragma unroll
        for (int j = 0; j < 4; ++j) acc[cc][i][j] *= al;
      // safe: all threads are past this iteration's kc barriers, so nobody is
      // still reading sP from the previous iteration.
      lds_st4(sP, ty * 4 + i, tx, 64, make_float4(s[i][0], s[i][1], s[i][2], s[i][3]));
    }

    // O += P @ Vtile, V cols chunked by 64; thread owns cols {cc*64 + tx*4..+3}
#pragma unroll
    for (int cc = 0; cc < 2; ++cc) {
      __syncthreads();  // P visible; previous sA readers done
      stage_tile<64, 64>(sA, Vt + cc * 64, 128, tid);
      __syncthreads();
#pragma unroll
      for (int sg = 0; sg < 16; ++sg) {
        float4 p4[4], v4[4];
#pragma unroll
        for (int i = 0; i < 4; ++i) p4[i] = lds_ld4(sP, ty * 4 + i, sg, 64);
#pragma unroll
        for (int sp = 0; sp < 4; ++sp) v4[sp] = lds_ld4(sA, sg * 4 + sp, tx, 64);
#pragma unroll
        for (int i = 0; i < 4; ++i) {
          acc[cc][i][0] += p4[i].x * v4[0].x + p4[i].y * v4[1].x + p4[i].z * v4[2].x +
                           p4[i].w * v4[3].x;
          acc[cc][i][1] += p4[i].x * v4[0].y + p4[i].y * v4[1].y + p4[i].z * v4[2].y +
                           p4[i].w * v4[3].y;
          acc[cc][i][2] += p4[i].x * v4[0].z + p4[i].y * v4[1].z + p4[i].z * v4[2].z +
                           p4[i].w * v4[3].z;
          acc[cc][i][3] += p4[i].x * v4[0].w + p4[i].y * v4[1].w + p4[i].z * v4[2].w +
                           p4[i].w * v4[3].w;
        }
      }
    }
  }

  // epilogue: normalize and write O as [b, t, h*128 + c]
  const int b = bh >> 3, h = bh & 7;
  const size_t base = ((size_t)b * Tn + (size_t)qt * 64) * (HEADS * Dn) + (size_t)h * Dn;
#pragma unroll
  for (int i = 0; i < 4; ++i) {
    const float inv = 1.0f / l[i];
#pragma unroll
    for (int cc = 0; cc < 2; ++cc) {
      float4 v = make_float4(acc[cc][i][0] * inv, acc[cc][i][1] * inv, acc[cc][i][2] * inv,
                             acc[cc][i][3] * inv);
      *reinterpret_cast<float4*>(Ob + base + (size_t)(ty * 4 + i) * (HEADS * Dn) + cc * 64 +
                                 tx * 4) = v;
    }
  }
}

// ---------------- output projection ----------------
// out[bt, j] = sum_i O[bt, i] * Wu[j, i] + bu[j]
__global__ __launch_bounds__(256) void outproj_kernel(const float* __restrict__ Ob,
                                                      const float* __restrict__ Wu,
                                                      const float* __restrict__ bu,
                                                      float* __restrict__ out) {
  __shared__ float sX[64 * 64];
  __shared__ float sW[64 * 64];
  const int tid = threadIdx.x;
  const int ty = tid >> 4, tx = tid & 15;
  const int r0 = blockIdx.x * 64;  // 0..8191
  const int c0 = blockIdx.y * 64;  // 0 or 64

  float acc[4][4] = {};
  for (int kc = 0; kc < 16; ++kc) {
    __syncthreads();
    stage_tile<64, 64>(sX, Ob + (size_t)r0 * 1024 + kc * 64, 1024, tid);
    stage_tile<64, 64>(sW, Wu + (size_t)c0 * 1024 + kc * 64, 1024, tid);
    __syncthreads();
    gemm64_step(sX, sW, ty, tx, acc);
  }

#pragma unroll
  for (int i = 0; i < 4; ++i) {
    float4 v;
    v.x = acc[i][0] + bu[c0 + tx * 4 + 0];
    v.y = acc[i][1] + bu[c0 + tx * 4 + 1];
    v.z = acc[i][2] + bu[c0 + tx * 4 + 2];
    v.w = acc[i][3] + bu[c0 + tx * 4 + 3];
    *reinterpret_cast<float4*>(out + (size_t)(r0 + ty * 4 + i) * Dn + c0 + tx * 4) = v;
  }
}

}  // namespace

extern "C" void kernel_launch(void* const* d_in, const int* in_sizes, int n_in, void* d_out,
                              int out_size, void* d_ws, size_t ws_size, hipStream_t stream) {
  (void)in_sizes; (void)n_in; (void)out_size; (void)ws_size;
  const float* x = (const float*)d_in[0];
  const float* Wq = (const float*)d_in[1];
  const float* Wk = (const float*)d_in[2];
  const float* Wv = (const float*)d_in[3];
  const float* Wu = (const float*)d_in[4];
  const float* bu = (const float*)d_in[5];
  float* out = (float*)d_out;

  constexpr size_t QKV_ELEMS = (size_t)Bn * HEADS * Tn * Dn;  // 8,388,608 floats = 32 MB
  float* ws = (float*)d_ws;
  float* Q = ws;
  float* Kb = ws + QKV_ELEMS;
  float* Vb = ws + 2 * QKV_ELEMS;
  float* Ob = ws + 3 * QKV_ELEMS;  // [b, t, h*128+d]

  proj_kernel<<<dim3(128, 48), 256, 0, stream>>>(x, Wq, Wk, Wv, Q, Kb, Vb);
  flash_kernel<<<dim3(32, 32), 256, 0, stream>>>(Q, Kb, Vb, Ob);
  outproj_kernel<<<dim3(128, 2), 256, 0, stream>>>(Ob, Wu, bu, out);
}

// Round 2
// 621.988 us; speedup vs baseline: 10.2248x; 10.2248x over previous
//
#include <hip/hip_runtime.h>
#include <cmath>

namespace {

constexpr int HEADS = 8;
constexpr int Bn = 4;
constexpr int Tn = 2048;
constexpr int Dn = 128;
constexpr float QK_SCALE = 0.2973017787506803f;  // 128^(-1/4)

typedef _Float16 half8 __attribute__((ext_vector_type(8)));
typedef _Float16 half4 __attribute__((ext_vector_type(4)));
typedef float f32x4 __attribute__((ext_vector_type(4)));

// ---------- fp32 GEMM helpers (proj / outproj), swizzled LDS ----------
__device__ __forceinline__ float4 lds_ld4(const float* buf, int r, int g, int ldw) {
  int gs = g ^ ((r >> 2) & 7);
  return *reinterpret_cast<const float4*>(buf + r * ldw + gs * 4);
}
__device__ __forceinline__ void lds_st4(float* buf, int r, int g, int ldw, float4 v) {
  int gs = g ^ ((r >> 2) & 7);
  *reinterpret_cast<float4*>(buf + r * ldw + gs * 4) = v;
}

template <int NROWS, int NCOLS>
__device__ __forceinline__ void stage_tile(float* dst, const float* src, int ld, int tid) {
  constexpr int NG = NCOLS / 4;
  constexpr int TOT = NROWS * NG;
#pragma unroll
  for (int fid = tid; fid < TOT; fid += 256) {
    int r = fid / NG;
    int g = fid % NG;
    float4 v = *reinterpret_cast<const float4*>(src + r * ld + g * 4);
    lds_st4(dst, r, g, NCOLS, v);
  }
}

__device__ __forceinline__ void gemm64_step(const float* sX, const float* sW, int ty, int tx,
                                            float acc[4][4]) {
#pragma unroll
  for (int g = 0; g < 16; ++g) {
    float4 a4[4], b4[4];
#pragma unroll
    for (int i = 0; i < 4; ++i) a4[i] = lds_ld4(sX, ty * 4 + i, g, 64);
#pragma unroll
    for (int j = 0; j < 4; ++j) b4[j] = lds_ld4(sW, tx * 4 + j, g, 64);
#pragma unroll
    for (int i = 0; i < 4; ++i)
#pragma unroll
      for (int j = 0; j < 4; ++j)
        acc[i][j] += a4[i].x * b4[j].x + a4[i].y * b4[j].y + a4[i].z * b4[j].z +
                     a4[i].w * b4[j].w;
  }
}

// ---------------- QKV projection (fp32 compute, fp16 output) ----------------
// Qh/Kh: [bh][t][d] fp16 (QK_SCALE folded). Vt: [bh][d][t] fp16 (transposed).
__global__ __launch_bounds__(256) void proj_kernel(
    const float* __restrict__ x, const float* __restrict__ Wq, const float* __restrict__ Wk,
    const float* __restrict__ Wv, _Float16* __restrict__ Qh, _Float16* __restrict__ Kh,
    _Float16* __restrict__ Vt) {
  __shared__ float sX[64 * 64];
  __shared__ float sW[64 * 64];
  const int tid = threadIdx.x;
  const int ty = tid >> 4, tx = tid & 15;
  const int rt = blockIdx.x;  // 0..127 over b*T
  const int ct = blockIdx.y;  // 0..47 over 3*1024
  const int sel = ct >> 4;
  const float* W = (sel == 0) ? Wq : (sel == 1) ? Wk : Wv;
  const float scale = (sel == 2) ? 1.0f : QK_SCALE;
  const int n0 = (ct & 15) * 64;
  const int r0 = rt * 64;

  float acc[4][4] = {};
#pragma unroll
  for (int kc = 0; kc < 2; ++kc) {
    __syncthreads();
    stage_tile<64, 64>(sX, x + (size_t)r0 * 128 + kc * 64, 128, tid);
    stage_tile<64, 64>(sW, W + (size_t)n0 * 128 + kc * 64, 128, tid);
    __syncthreads();
    gemm64_step(sX, sW, ty, tx, acc);
  }

  const int b = r0 >> 11;
  const int t0 = r0 & 2047;
  const int h = n0 >> 7;
  const int d0 = n0 & 127;
  const int bh = b * HEADS + h;

  if (sel < 2) {
    _Float16* dst = (sel == 0) ? Qh : Kh;
#pragma unroll
    for (int i = 0; i < 4; ++i) {
      const int t = t0 + ty * 4 + i;
      half4 hv;
      hv.x = (_Float16)(acc[i][0] * scale);
      hv.y = (_Float16)(acc[i][1] * scale);
      hv.z = (_Float16)(acc[i][2] * scale);
      hv.w = (_Float16)(acc[i][3] * scale);
      *reinterpret_cast<half4*>(dst + ((size_t)bh * Tn + t) * Dn + d0 + tx * 4) = hv;
    }
  } else {
    // transpose: Vt[bh][d][t]
#pragma unroll
    for (int j = 0; j < 4; ++j) {
      const int d = d0 + tx * 4 + j;
      half4 hv;
      hv.x = (_Float16)acc[0][j];
      hv.y = (_Float16)acc[1][j];
      hv.z = (_Float16)acc[2][j];
      hv.w = (_Float16)acc[3][j];
      *reinterpret_cast<half4*>(Vt + ((size_t)bh * Dn + d) * Tn + t0 + ty * 4) = hv;
    }
  }
}

// ---------------- fp16 MFMA flash attention ----------------
// grid (32 qtiles, 32 bh); 4 waves/block, 16 q-rows per wave.
// LDS: sK 16KB + sV 16KB + sP 8KB = 40KB -> 4 blocks/CU.
__global__ __launch_bounds__(256, 4) void flash_kernel(const _Float16* __restrict__ Qh,
                                                       const _Float16* __restrict__ Kh,
                                                       const _Float16* __restrict__ Vt,
                                                       float* __restrict__ Ob) {
  __shared__ _Float16 sK[64 * 128];      // K tile, 16B groups swizzled: p = g ^ (r&15)
  __shared__ _Float16 sV[128 * 64];      // Vt tile, 8 groups: p = g ^ ((r&7)^((r>>1)&4))
  __shared__ _Float16 sP[4][16 * 64];    // per-wave P

  const int tid = threadIdx.x;
  const int w = tid >> 6;
  const int lane = tid & 63;
  const int quad = lane >> 4;
  const int l16 = lane & 15;
  const int qt = blockIdx.x;
  const int bh = blockIdx.y;

  // Q A-fragments in registers: lane holds Q[q0 + l16][kk*32 + quad*8 .. +7]
  const _Float16* Qp = Qh + ((size_t)bh * Tn + qt * 64 + w * 16 + l16) * Dn;
  half8 qf[4];
#pragma unroll
  for (int kk = 0; kk < 4; ++kk)
    qf[kk] = *reinterpret_cast<const half8*>(Qp + kk * 32 + quad * 8);

  const _Float16* Kp = Kh + (size_t)bh * Tn * Dn;
  const _Float16* Vp = Vt + (size_t)bh * Dn * Tn;
  _Float16* sPw = sP[w];

  f32x4 o[8];
#pragma unroll
  for (int nt = 0; nt < 8; ++nt) o[nt] = (f32x4){0.f, 0.f, 0.f, 0.f};
  float m[4], l[4];
#pragma unroll
  for (int r = 0; r < 4; ++r) { m[r] = -1e30f; l[r] = 0.0f; }

  for (int st = 0; st < Tn / 64; ++st) {
    __syncthreads();
    // stage K tile: 64 rows x 128 halfs (256B/row, 16 groups of 16B)
    {
      const _Float16* src = Kp + (size_t)st * 64 * Dn;
#pragma unroll
      for (int it = 0; it < 4; ++it) {
        int fid = tid + it * 256;
        int r = fid >> 4, g = fid & 15;
        float4 v = *reinterpret_cast<const float4*>(src + r * Dn + g * 8);
        int p = g ^ (r & 15);
        *reinterpret_cast<float4*>(sK + r * 128 + p * 8) = v;
      }
      // stage V tile: 128 rows (d) x 64 halfs (128B/row, 8 groups of 16B)
      const _Float16* vsrc = Vp + st * 64;
#pragma unroll
      for (int it = 0; it < 4; ++it) {
        int fid = tid + it * 256;
        int r = fid >> 3, g = fid & 7;
        float4 v = *reinterpret_cast<const float4*>(vsrc + (size_t)r * Tn + g * 8);
        int p = g ^ ((r & 7) ^ ((r >> 1) & 4));
        *reinterpret_cast<float4*>(sV + r * 64 + p * 8) = v;
      }
    }
    __syncthreads();

    // S(16x64) = Q_tile x K_tile^T ; col-tile j holds cols j*16..+15
    f32x4 s[4];
#pragma unroll
    for (int j = 0; j < 4; ++j) s[j] = (f32x4){0.f, 0.f, 0.f, 0.f};
#pragma unroll
    for (int kk = 0; kk < 4; ++kk) {
#pragma unroll
      for (int j = 0; j < 4; ++j) {
        int r = j * 16 + l16;
        int p = (kk * 4 + quad) ^ (r & 15);
        half8 kf = *reinterpret_cast<const half8*>(sK + r * 128 + p * 8);
        s[j] = __builtin_amdgcn_mfma_f32_16x16x32_f16(qf[kk], kf, s[j], 0, 0, 0);
      }
    }

    // online softmax; lane's reg r is q-row quad*4+r; cols spread over 16 lanes
#pragma unroll
    for (int r = 0; r < 4; ++r) {
      float mt = fmaxf(fmaxf(s[0][r], s[1][r]), fmaxf(s[2][r], s[3][r]));
#pragma unroll
      for (int off = 8; off; off >>= 1) mt = fmaxf(mt, __shfl_xor(mt, off, 16));
      const float mn = fmaxf(m[r], mt);
      const float al = __expf(m[r] - mn);
      float p0 = __expf(s[0][r] - mn);
      float p1 = __expf(s[1][r] - mn);
      float p2 = __expf(s[2][r] - mn);
      float p3 = __expf(s[3][r] - mn);
      float rs = (p0 + p1) + (p2 + p3);
#pragma unroll
      for (int off = 8; off; off >>= 1) rs += __shfl_xor(rs, off, 16);
      l[r] = l[r] * al + rs;
      m[r] = mn;
#pragma unroll
      for (int nt = 0; nt < 8; ++nt) o[nt][r] *= al;

      const int row = quad * 4 + r;
      const int rswz = (row & 7) ^ ((row >> 1) & 4);
      float pv[4] = {p0, p1, p2, p3};
#pragma unroll
      for (int j = 0; j < 4; ++j) {
        int col = j * 16 + l16;
        int g = col >> 3;
        int p = g ^ rswz;
        sPw[row * 64 + p * 8 + (col & 7)] = (_Float16)pv[j];
      }
    }

    // O(16x128) += P(16x64) x V(64x128); sP is wave-private (no barrier needed)
#pragma unroll
    for (int kk2 = 0; kk2 < 2; ++kk2) {
      const int gA = kk2 * 4 + quad;
      const int pA = gA ^ ((l16 & 7) ^ ((l16 >> 1) & 4));
      half8 pf = *reinterpret_cast<const half8*>(sPw + l16 * 64 + pA * 8);
#pragma unroll
      for (int nt = 0; nt < 8; ++nt) {
        int r = nt * 16 + l16;
        int pV = gA ^ ((r & 7) ^ ((r >> 1) & 4));
        half8 vf = *reinterpret_cast<const half8*>(sV + r * 64 + pV * 8);
        o[nt] = __builtin_amdgcn_mfma_f32_16x16x32_f16(pf, vf, o[nt], 0, 0, 0);
      }
    }
  }

  // epilogue: O row = qt*64 + w*16 + quad*4 + r, col = h*128 + nt*16 + l16
  const int b = bh >> 3, h = bh & 7;
#pragma unroll
  for (int r = 0; r < 4; ++r) {
    const float inv = 1.0f / l[r];
    const size_t trow = (size_t)(b * Tn + qt * 64 + w * 16 + quad * 4 + r) * (HEADS * Dn);
#pragma unroll
    for (int nt = 0; nt < 8; ++nt)
      Ob[trow + h * Dn + nt * 16 + l16] = o[nt][r] * inv;
  }
}

// ---------------- output projection (fp32) ----------------
__global__ __launch_bounds__(256) void outproj_kernel(const float* __restrict__ Ob,
                                                      const float* __restrict__ Wu,
                                                      const float* __restrict__ bu,
                                                      float* __restrict__ out) {
  __shared__ float sX[64 * 64];
  __shared__ float sW[64 * 64];
  const int tid = threadIdx.x;
  const int ty = tid >> 4, tx = tid & 15;
  const int r0 = blockIdx.x * 64;
  const int c0 = blockIdx.y * 64;

  float acc[4][4] = {};
  for (int kc = 0; kc < 16; ++kc) {
    __syncthreads();
    stage_tile<64, 64>(sX, Ob + (size_t)r0 * 1024 + kc * 64, 1024, tid);
    stage_tile<64, 64>(sW, Wu + (size_t)c0 * 1024 + kc * 64, 1024, tid);
    __syncthreads();
    gemm64_step(sX, sW, ty, tx, acc);
  }

#pragma unroll
  for (int i = 0; i < 4; ++i) {
    float4 v;
    v.x = acc[i][0] + bu[c0 + tx * 4 + 0];
    v.y = acc[i][1] + bu[c0 + tx * 4 + 1];
    v.z = acc[i][2] + bu[c0 + tx * 4 + 2];
    v.w = acc[i][3] + bu[c0 + tx * 4 + 3];
    *reinterpret_cast<float4*>(out + (size_t)(r0 + ty * 4 + i) * Dn + c0 + tx * 4) = v;
  }
}

}  // namespace

extern "C" void kernel_launch(void* const* d_in, const int* in_sizes, int n_in, void* d_out,
                              int out_size, void* d_ws, size_t ws_size, hipStream_t stream) {
  (void)in_sizes; (void)n_in; (void)out_size; (void)ws_size;
  const float* x = (const float*)d_in[0];
  const float* Wq = (const float*)d_in[1];
  const float* Wk = (const float*)d_in[2];
  const float* Wv = (const float*)d_in[3];
  const float* Wu = (const float*)d_in[4];
  const float* bu = (const float*)d_in[5];
  float* out = (float*)d_out;

  constexpr size_t NE = (size_t)Bn * HEADS * Tn * Dn;  // 8,388,608 elements
  char* ws = (char*)d_ws;
  _Float16* Qh = (_Float16*)ws;                        // 16.78 MB
  _Float16* Kh = (_Float16*)(ws + NE * 2);             // 16.78 MB
  _Float16* Vt = (_Float16*)(ws + NE * 4);             // 16.78 MB
  float* Ob = (float*)(ws + NE * 6);                   // 33.55 MB fp32

  proj_kernel<<<dim3(128, 48), 256, 0, stream>>>(x, Wq, Wk, Wv, Qh, Kh, Vt);
  flash_kernel<<<dim3(32, 32), 256, 0, stream>>>(Qh, Kh, Vt, Ob);
  outproj_kernel<<<dim3(128, 2), 256, 0, stream>>>(Ob, Wu, bu, out);
}

// Round 4
// 268.240 us; speedup vs baseline: 23.7091x; 2.3188x over previous
//
#include <hip/hip_runtime.h>
#include <cmath>

namespace {

constexpr int HEADS = 8;
constexpr int Bn = 4;
constexpr int Tn = 2048;
constexpr int Dn = 128;
constexpr float QK_SCALE = 0.2973017787506803f;  // 128^(-1/4)

typedef _Float16 half8 __attribute__((ext_vector_type(8)));
typedef float f32x4 __attribute__((ext_vector_type(4)));

// ---------------- cast inputs to fp16 ----------------
// x: 4*2048*128 = 1,048,576 floats. WH layout: [Wq(1024x128)][Wk][Wv][Wu(128x1024)],
// 4 x 131,072 = 524,288 halfs. Total 1,572,864 elements -> 196,608 threads -> 768 blocks.
__global__ __launch_bounds__(256) void cast_kernel(
    const float* __restrict__ x, const float* __restrict__ Wq, const float* __restrict__ Wk,
    const float* __restrict__ Wv, const float* __restrict__ Wu, _Float16* __restrict__ xh,
    _Float16* __restrict__ WH) {
  const int idx = blockIdx.x * 256 + threadIdx.x;
  const size_t base = (size_t)idx * 8;
  const float* src;
  _Float16* dst;
  if (base < 1048576) {
    src = x + base;
    dst = xh + base;
  } else {
    const size_t r = base - 1048576;
    const int s = (int)(r >> 17);  // each W chunk = 131,072 elements
    src = ((s == 0) ? Wq : (s == 1) ? Wk : (s == 2) ? Wv : Wu) + (r & 131071);
    dst = WH + r;
  }
  const float4 a = *reinterpret_cast<const float4*>(src);
  const float4 b = *reinterpret_cast<const float4*>(src + 4);
  half8 h;
  h[0] = (_Float16)a.x; h[1] = (_Float16)a.y; h[2] = (_Float16)a.z; h[3] = (_Float16)a.w;
  h[4] = (_Float16)b.x; h[5] = (_Float16)b.y; h[6] = (_Float16)b.z; h[7] = (_Float16)b.w;
  *reinterpret_cast<half8*>(dst) = h;
}

// ---------------- QKV projection, fp16 MFMA ----------------
// grid (64 M-tiles over b*T, 24 N-tiles over 3*1024). Block 256 thr / 4 waves.
// Qh/Kh: [bh][t][d] (QK_SCALE folded). Vt: [bh][d][t].
__global__ __launch_bounds__(256, 4) void proj_kernel(const _Float16* __restrict__ xh,
                                                      const _Float16* __restrict__ WH,
                                                      _Float16* __restrict__ Qh,
                                                      _Float16* __restrict__ Kh,
                                                      _Float16* __restrict__ Vt) {
  // phase 1: W-tile 128x128, 16B-chunk swizzle p = g ^ (r&15)
  // phase 2: C-stage 128x136 (pad 8 halfs)
  __shared__ _Float16 sB[128 * 136];  // 34.8 KB
  const int tid = threadIdx.x;
  const int w = tid >> 6, lane = tid & 63, quad = lane >> 4, l16 = lane & 15;
  const int m0 = blockIdx.x * 128;
  const int n0 = blockIdx.y * 128;

  // stage W tile (coalesced 16B loads)
#pragma unroll
  for (int it = 0; it < 8; ++it) {
    const int fid = tid + it * 256;
    const int r = fid >> 4, g = fid & 15;
    const half8 v = *reinterpret_cast<const half8*>(WH + (size_t)(n0 + r) * 128 + g * 8);
    const int p = g ^ (r & 15);
    *reinterpret_cast<half8*>(sB + r * 128 + p * 8) = v;
  }

  // A fragments straight from global (xh is 2MB, L2-hot): wave w owns rows m0+w*32..+31
  half8 af[2][4];
  const _Float16* xp = xh + (size_t)(m0 + w * 32 + l16) * 128 + quad * 8;
#pragma unroll
  for (int mt = 0; mt < 2; ++mt)
#pragma unroll
    for (int kk = 0; kk < 4; ++kk)
      af[mt][kk] = *reinterpret_cast<const half8*>(xp + mt * 16 * 128 + kk * 32);

  __syncthreads();

  f32x4 acc[2][8];
#pragma unroll
  for (int mt = 0; mt < 2; ++mt)
#pragma unroll
    for (int nt = 0; nt < 8; ++nt) acc[mt][nt] = (f32x4){0.f, 0.f, 0.f, 0.f};

#pragma unroll
  for (int kk = 0; kk < 4; ++kk)
#pragma unroll
    for (int nt = 0; nt < 8; ++nt) {
      const int r = nt * 16 + l16;
      const int p = (kk * 4 + quad) ^ l16;  // r&15 == l16
      const half8 bf = *reinterpret_cast<const half8*>(sB + r * 128 + p * 8);
      acc[0][nt] = __builtin_amdgcn_mfma_f32_16x16x32_f16(af[0][kk], bf, acc[0][nt], 0, 0, 0);
      acc[1][nt] = __builtin_amdgcn_mfma_f32_16x16x32_f16(af[1][kk], bf, acc[1][nt], 0, 0, 0);
    }

  const int sel = n0 >> 10;
  const int h = (n0 >> 7) & 7;
  const int b = m0 >> 11;
  const int t0b = m0 & 2047;
  const int bh = b * HEADS + h;
  const float scale = (sel == 2) ? 1.0f : QK_SCALE;

  __syncthreads();  // done with W tile; reuse sB as C-stage

  if (sel < 2) {
    // sC[t_local][d], stride 136
#pragma unroll
    for (int mt = 0; mt < 2; ++mt)
#pragma unroll
      for (int nt = 0; nt < 8; ++nt)
#pragma unroll
        for (int r = 0; r < 4; ++r)
          sB[(w * 32 + mt * 16 + quad * 4 + r) * 136 + nt * 16 + l16] =
              (_Float16)(acc[mt][nt][r] * scale);
  } else {
    // transpose: sC[d][t_local], stride 136
#pragma unroll
    for (int mt = 0; mt < 2; ++mt)
#pragma unroll
      for (int nt = 0; nt < 8; ++nt)
#pragma unroll
        for (int r = 0; r < 4; ++r)
          sB[(nt * 16 + l16) * 136 + w * 32 + mt * 16 + quad * 4 + r] = (_Float16)acc[mt][nt][r];
  }
  __syncthreads();

  _Float16* dstbase;
  size_t rstride;
  if (sel == 0) {
    dstbase = Qh + ((size_t)bh * Tn + t0b) * Dn;
    rstride = Dn;
  } else if (sel == 1) {
    dstbase = Kh + ((size_t)bh * Tn + t0b) * Dn;
    rstride = Dn;
  } else {
    dstbase = Vt + ((size_t)bh * Dn) * Tn + t0b;
    rstride = Tn;
  }
  // coalesced 256B-row stores, no write amplification
#pragma unroll
  for (int it = 0; it < 8; ++it) {
    const int fid = tid + it * 256;
    const int r = fid >> 4, g = fid & 15;
    const half8 v = *reinterpret_cast<const half8*>(sB + r * 136 + g * 8);
    *reinterpret_cast<half8*>(dstbase + (size_t)r * rstride + g * 8) = v;
  }
}

// ---------------- fp16 MFMA flash attention ----------------
// grid (32 qtiles, 32 bh); 4 waves/block, 16 q-rows per wave. LDS 40KB.
__global__ __launch_bounds__(256, 4) void flash_kernel(const _Float16* __restrict__ Qh,
                                                       const _Float16* __restrict__ Kh,
                                                       const _Float16* __restrict__ Vt,
                                                       _Float16* __restrict__ Obh) {
  __shared__ _Float16 sK[64 * 128];    // p = g ^ (r&15)
  __shared__ _Float16 sV[128 * 64];    // p = g ^ ((r&7)^((r>>1)&4))
  __shared__ _Float16 sP[4][16 * 64];  // per-wave P

  const int tid = threadIdx.x;
  const int w = tid >> 6;
  const int lane = tid & 63;
  const int quad = lane >> 4;
  const int l16 = lane & 15;
  const int qt = blockIdx.x;
  const int bh = blockIdx.y;

  const _Float16* Qp = Qh + ((size_t)bh * Tn + qt * 64 + w * 16 + l16) * Dn;
  half8 qf[4];
#pragma unroll
  for (int kk = 0; kk < 4; ++kk)
    qf[kk] = *reinterpret_cast<const half8*>(Qp + kk * 32 + quad * 8);

  const _Float16* Kp = Kh + (size_t)bh * Tn * Dn;
  const _Float16* Vp = Vt + (size_t)bh * Dn * Tn;
  _Float16* sPw = sP[w];

  f32x4 o[8];
#pragma unroll
  for (int nt = 0; nt < 8; ++nt) o[nt] = (f32x4){0.f, 0.f, 0.f, 0.f};
  float m[4], l[4];
#pragma unroll
  for (int r = 0; r < 4; ++r) { m[r] = -1e30f; l[r] = 0.0f; }

  for (int st = 0; st < Tn / 64; ++st) {
    __syncthreads();
    {
      const _Float16* src = Kp + (size_t)st * 64 * Dn;
#pragma unroll
      for (int it = 0; it < 4; ++it) {
        int fid = tid + it * 256;
        int r = fid >> 4, g = fid & 15;
        float4 v = *reinterpret_cast<const float4*>(src + r * Dn + g * 8);
        int p = g ^ (r & 15);
        *reinterpret_cast<float4*>(sK + r * 128 + p * 8) = v;
      }
      const _Float16* vsrc = Vp + st * 64;
#pragma unroll
      for (int it = 0; it < 4; ++it) {
        int fid = tid + it * 256;
        int r = fid >> 3, g = fid & 7;
        float4 v = *reinterpret_cast<const float4*>(vsrc + (size_t)r * Tn + g * 8);
        int p = g ^ ((r & 7) ^ ((r >> 1) & 4));
        *reinterpret_cast<float4*>(sV + r * 64 + p * 8) = v;
      }
    }
    __syncthreads();

    f32x4 s[4];
#pragma unroll
    for (int j = 0; j < 4; ++j) s[j] = (f32x4){0.f, 0.f, 0.f, 0.f};
#pragma unroll
    for (int kk = 0; kk < 4; ++kk) {
#pragma unroll
      for (int j = 0; j < 4; ++j) {
        int r = j * 16 + l16;
        int p = (kk * 4 + quad) ^ (r & 15);
        half8 kf = *reinterpret_cast<const half8*>(sK + r * 128 + p * 8);
        s[j] = __builtin_amdgcn_mfma_f32_16x16x32_f16(qf[kk], kf, s[j], 0, 0, 0);
      }
    }

#pragma unroll
    for (int r = 0; r < 4; ++r) {
      float mt = fmaxf(fmaxf(s[0][r], s[1][r]), fmaxf(s[2][r], s[3][r]));
#pragma unroll
      for (int off = 8; off; off >>= 1) mt = fmaxf(mt, __shfl_xor(mt, off, 16));
      const float mn = fmaxf(m[r], mt);
      const float al = __expf(m[r] - mn);
      float p0 = __expf(s[0][r] - mn);
      float p1 = __expf(s[1][r] - mn);
      float p2 = __expf(s[2][r] - mn);
      float p3 = __expf(s[3][r] - mn);
      float rs = (p0 + p1) + (p2 + p3);
#pragma unroll
      for (int off = 8; off; off >>= 1) rs += __shfl_xor(rs, off, 16);
      l[r] = l[r] * al + rs;
      m[r] = mn;
#pragma unroll
      for (int nt = 0; nt < 8; ++nt) o[nt][r] *= al;

      const int row = quad * 4 + r;
      const int rswz = (row & 7) ^ ((row >> 1) & 4);
      float pv[4] = {p0, p1, p2, p3};
#pragma unroll
      for (int j = 0; j < 4; ++j) {
        int col = j * 16 + l16;
        int g = col >> 3;
        int p = g ^ rswz;
        sPw[row * 64 + p * 8 + (col & 7)] = (_Float16)pv[j];
      }
    }

#pragma unroll
    for (int kk2 = 0; kk2 < 2; ++kk2) {
      const int gA = kk2 * 4 + quad;
      const int pA = gA ^ ((l16 & 7) ^ ((l16 >> 1) & 4));
      half8 pf = *reinterpret_cast<const half8*>(sPw + l16 * 64 + pA * 8);
#pragma unroll
      for (int nt = 0; nt < 8; ++nt) {
        int r = nt * 16 + l16;
        int pV = gA ^ ((r & 7) ^ ((r >> 1) & 4));
        half8 vf = *reinterpret_cast<const half8*>(sV + r * 64 + pV * 8);
        o[nt] = __builtin_amdgcn_mfma_f32_16x16x32_f16(pf, vf, o[nt], 0, 0, 0);
      }
    }
  }

  // epilogue -> fp16 O [b][t][h*128+d]
  const int b = bh >> 3, h = bh & 7;
#pragma unroll
  for (int r = 0; r < 4; ++r) {
    const float inv = 1.0f / l[r];
    const size_t trow = (size_t)(b * Tn + qt * 64 + w * 16 + quad * 4 + r) * (HEADS * Dn);
#pragma unroll
    for (int nt = 0; nt < 8; ++nt)
      Obh[trow + h * Dn + nt * 16 + l16] = (_Float16)(o[nt][r] * inv);
  }
}

// ---------------- output projection, fp16 MFMA, wave-split-K ----------------
// grid 256 blocks; block handles 32 rows x 128 cols; wave w covers K [w*256,+256).
__global__ __launch_bounds__(256, 4) void outproj_kernel(const _Float16* __restrict__ Obh,
                                                         const _Float16* __restrict__ Wuh,
                                                         const float* __restrict__ bu,
                                                         float* __restrict__ out) {
  __shared__ float sR[4 * 32 * 128];  // 64 KB partials
  const int tid = threadIdx.x;
  const int w = tid >> 6, lane = tid & 63, quad = lane >> 4, l16 = lane & 15;
  const int r0 = blockIdx.x * 32;

  f32x4 acc[2][8];
#pragma unroll
  for (int mt = 0; mt < 2; ++mt)
#pragma unroll
    for (int nt = 0; nt < 8; ++nt) acc[mt][nt] = (f32x4){0.f, 0.f, 0.f, 0.f};

  const _Float16* ap = Obh + (size_t)(r0 + l16) * 1024 + w * 256 + quad * 8;
  const _Float16* bp = Wuh + (size_t)l16 * 1024 + w * 256 + quad * 8;

#pragma unroll
  for (int kk = 0; kk < 8; ++kk) {
    const half8 a0 = *reinterpret_cast<const half8*>(ap + kk * 32);
    const half8 a1 = *reinterpret_cast<const half8*>(ap + 16 * 1024 + kk * 32);
#pragma unroll
    for (int nt = 0; nt < 8; ++nt) {
      const half8 bf = *reinterpret_cast<const half8*>(bp + (size_t)nt * 16 * 1024 + kk * 32);
      acc[0][nt] = __builtin_amdgcn_mfma_f32_16x16x32_f16(a0, bf, acc[0][nt], 0, 0, 0);
      acc[1][nt] = __builtin_amdgcn_mfma_f32_16x16x32_f16(a1, bf, acc[1][nt], 0, 0, 0);
    }
  }

#pragma unroll
  for (int mt = 0; mt < 2; ++mt)
#pragma unroll
    for (int nt = 0; nt < 8; ++nt)
#pragma unroll
      for (int r = 0; r < 4; ++r)
        sR[w * 4096 + (mt * 16 + quad * 4 + r) * 128 + nt * 16 + l16] = acc[mt][nt][r];
  __syncthreads();

#pragma unroll
  for (int it = 0; it < 16; ++it) {
    const int idx = tid + it * 256;  // 0..4095
    const int row = idx >> 7, col = idx & 127;
    const float v =
        sR[idx] + sR[4096 + idx] + sR[8192 + idx] + sR[12288 + idx] + bu[col];
    out[(size_t)(r0 + row) * Dn + col] = v;
  }
}

}  // namespace

extern "C" void kernel_launch(void* const* d_in, const int* in_sizes, int n_in, void* d_out,
                              int out_size, void* d_ws, size_t ws_size, hipStream_t stream) {
  (void)in_sizes; (void)n_in; (void)out_size; (void)ws_size;
  const float* x = (const float*)d_in[0];
  const float* Wq = (const float*)d_in[1];
  const float* Wk = (const float*)d_in[2];
  const float* Wv = (const float*)d_in[3];
  const float* Wu = (const float*)d_in[4];
  const float* bu = (const float*)d_in[5];
  float* out = (float*)d_out;

  constexpr size_t NE = (size_t)Bn * HEADS * Tn * Dn;  // 8,388,608 elements
  char* ws = (char*)d_ws;
  _Float16* xh = (_Float16*)ws;                        // 2 MB  (1,048,576 halfs)
  _Float16* WH = (_Float16*)(ws + 2097152);            // 1 MB  [Wq][Wk][Wv][Wu]
  _Float16* Qh = (_Float16*)(ws + 4194304);            // 16 MB
  _Float16* Kh = (_Float16*)(ws + 4194304 + NE * 2);   // 16 MB
  _Float16* Vt = (_Float16*)(ws + 4194304 + NE * 4);   // 16 MB
  _Float16* Obh = (_Float16*)(ws + 4194304 + NE * 6);  // 16 MB
  _Float16* Wuh = WH + 393216;

  cast_kernel<<<dim3(768), 256, 0, stream>>>(x, Wq, Wk, Wv, Wu, xh, WH);
  proj_kernel<<<dim3(64, 24), 256, 0, stream>>>(xh, WH, Qh, Kh, Vt);
  flash_kernel<<<dim3(32, 32), 256, 0, stream>>>(Qh, Kh, Vt, Obh);
  outproj_kernel<<<dim3(256), 256, 0, stream>>>(Obh, Wuh, bu, out);
}